// Round 3
// baseline (320.552 us; speedup 1.0000x reference)
//
#include <hip/hip_runtime.h>

#define N_NODES 50000
#define IN_DIM 64
#define OUT_DIM 128
#define N_EDGES 800000
#define NTILES ((N_NODES + 255) / 256)   // 196

// ---------------- Phase 1: histogram of dst into offs (counts) ----------------
__global__ __launch_bounds__(256) void hist_k(const int* __restrict__ ei, int* __restrict__ offs)
{
    int e = blockIdx.x * 256 + threadIdx.x;
    if (e < N_EDGES) atomicAdd(&offs[ei[N_EDGES + e]], 1);
}

// ---------------- Phase 2a: per-tile sums ----------------
__global__ __launch_bounds__(256) void tile_sum(const int* __restrict__ offs, int* __restrict__ partials)
{
    __shared__ int ws[4];
    int t = threadIdx.x, lane = t & 63, wid = t >> 6;
    int i = blockIdx.x * 256 + t;
    int v = (i < N_NODES) ? offs[i] : 0;
#pragma unroll
    for (int d = 32; d >= 1; d >>= 1) v += __shfl_down(v, d, 64);
    if (lane == 0) ws[wid] = v;
    __syncthreads();
    if (t == 0) partials[blockIdx.x] = ws[0] + ws[1] + ws[2] + ws[3];
}

// ---------------- Phase 2b: exclusive scan of tile partials (1 wave) ----------------
__global__ __launch_bounds__(64) void scan_partials(int* __restrict__ p)
{
    int lane = threadIdx.x;
    int carry = 0;
    for (int base = 0; base < NTILES; base += 64) {
        int i = base + lane;
        int v = (i < NTILES) ? p[i] : 0;
        int incl = v;
#pragma unroll
        for (int d = 1; d < 64; d <<= 1) {
            int u = __shfl_up(incl, d, 64);
            if (lane >= d) incl += u;
        }
        if (i < NTILES) p[i] = carry + incl - v;
        carry += __shfl(incl, 63, 64);
    }
}

// ---------------- Phase 2c: per-tile exclusive rescan + add partial ----------------
__global__ __launch_bounds__(256) void scan_tile(int* __restrict__ offs, const int* __restrict__ partials)
{
    __shared__ int wsum[4];
    int t = threadIdx.x, lane = t & 63, wid = t >> 6;
    int i = blockIdx.x * 256 + t;
    int v = (i < N_NODES) ? offs[i] : 0;
    int incl = v;
#pragma unroll
    for (int d = 1; d < 64; d <<= 1) {
        int u = __shfl_up(incl, d, 64);
        if (lane >= d) incl += u;
    }
    if (lane == 63) wsum[wid] = incl;
    __syncthreads();
    int waveoff = 0;
    for (int w = 0; w < wid; ++w) waveoff += wsum[w];
    if (i < N_NODES) offs[i] = partials[blockIdx.x] + waveoff + incl - v;
}

// ---------------- Phase 3: binning (starts -> ends as side effect) ----------------
__global__ __launch_bounds__(256) void bin_k(const int* __restrict__ ei,
                                             int* __restrict__ offs, int* __restrict__ srcs)
{
    int e = blockIdx.x * 256 + threadIdx.x;
    if (e < N_EDGES) {
        int dst = ei[N_EDGES + e];
        int pos = atomicAdd(&offs[dst], 1);
        srcs[pos] = ei[e];
    }
}

// ---------------- Phase 4: gather + mean (wave per node, lane = feature) ----------------
__global__ __launch_bounds__(256) void gather_k(const float* __restrict__ x,
                                                const int* __restrict__ offs,
                                                const int* __restrict__ srcs,
                                                float* __restrict__ mean)
{
    int gw = (blockIdx.x * 256 + threadIdx.x) >> 6;   // global wave id = node
    int lane = threadIdx.x & 63;
    if (gw >= N_NODES) return;
    int n = gw;
    int end = offs[n];
    int start = n ? offs[n - 1] : 0;
    float acc = 0.f;
    int j = start;
    while (j < end) {
        int m = end - j; if (m > 64) m = 64;
        int sv = (lane < m) ? srcs[j + lane] : 0;
        int kk = 0;
        for (; kk + 4 <= m; kk += 4) {
            int s0 = __shfl(sv, kk + 0, 64);
            int s1 = __shfl(sv, kk + 1, 64);
            int s2 = __shfl(sv, kk + 2, 64);
            int s3 = __shfl(sv, kk + 3, 64);
            float a0 = x[(size_t)s0 * IN_DIM + lane];
            float a1 = x[(size_t)s1 * IN_DIM + lane];
            float a2 = x[(size_t)s2 * IN_DIM + lane];
            float a3 = x[(size_t)s3 * IN_DIM + lane];
            acc += (a0 + a1) + (a2 + a3);
        }
        for (; kk < m; ++kk) {
            int s = __shfl(sv, kk, 64);
            acc += x[(size_t)s * IN_DIM + lane];
        }
        j += m;
    }
    int deg = end - start;
    float inv = deg ? 1.0f / (float)deg : 0.0f;
    mean[(size_t)n * IN_DIM + lane] = acc * inv;
}

// ---------------- Phase 5: fused linear, path-split ----------------
// threads 0..127: accR = x[n].Wr[o];  threads 128..255: accL = mean[n].Wl[o]
// combine via LDS; each thread holds only 64 weight VGPRs so both matrices
// stay register-resident.
__global__ __launch_bounds__(256) void sage_linear2(
    const float* __restrict__ x, const float* __restrict__ mean,
    const float* __restrict__ Wl, const float* __restrict__ bl,
    const float* __restrict__ Wr, float* __restrict__ out)
{
    __shared__ float lbuf[128];
    int t = threadIdx.x;
    bool pathL = (t >= 128);          // wave-uniform (waves 2,3)
    int o = t & 127;

    const float* Wrow = (pathL ? Wl : Wr) + (size_t)o * IN_DIM;
    float4 w[16];
#pragma unroll
    for (int c = 0; c < 16; ++c) w[c] = ((const float4*)Wrow)[c];
    float bias = pathL ? 0.f : bl[o];
    const float* rowbase = pathL ? mean : x;

    for (int n = blockIdx.x; n < N_NODES; n += gridDim.x) {
        const float4* rp = (const float4*)(rowbase + (size_t)n * IN_DIM);
        float acc = 0.f;
#pragma unroll
        for (int c = 0; c < 16; ++c) {
            float4 rv = rp[c];    // wave-uniform address -> s_load broadcast
            acc = fmaf(rv.x, w[c].x, acc);
            acc = fmaf(rv.y, w[c].y, acc);
            acc = fmaf(rv.z, w[c].z, acc);
            acc = fmaf(rv.w, w[c].w, acc);
        }
        if (pathL) lbuf[o] = acc;
        __syncthreads();
        if (!pathL) out[(size_t)n * OUT_DIM + o] = acc + bias + lbuf[o];
        __syncthreads();
    }
}

extern "C" void kernel_launch(void* const* d_in, const int* in_sizes, int n_in,
                              void* d_out, int out_size, void* d_ws, size_t ws_size,
                              hipStream_t stream) {
    const float* x  = (const float*)d_in[0];
    const int*   ei = (const int*)d_in[1];
    const float* Wl = (const float*)d_in[2];
    const float* bl = (const float*)d_in[3];
    const float* Wr = (const float*)d_in[4];
    float* out = (float*)d_out;

    // ws layout: offs[int x 50000] | srcs[int x 800000] | mean[float x 3.2M] | partials[int x 196]
    int*   offs = (int*)d_ws;
    int*   srcs = offs + N_NODES;
    float* mean = (float*)(srcs + N_EDGES);
    int*   partials = (int*)(mean + (size_t)N_NODES * IN_DIM);

    hipMemsetAsync(offs, 0, (size_t)N_NODES * sizeof(int), stream);

    int eb = (N_EDGES + 255) / 256;                 // 3125
    hist_k<<<eb, 256, 0, stream>>>(ei, offs);
    tile_sum<<<NTILES, 256, 0, stream>>>(offs, partials);
    scan_partials<<<1, 64, 0, stream>>>(partials);
    scan_tile<<<NTILES, 256, 0, stream>>>(offs, partials);
    bin_k<<<eb, 256, 0, stream>>>(ei, offs, srcs);

    int gb = (N_NODES * 64 + 255) / 256;            // 12500
    gather_k<<<gb, 256, 0, stream>>>(x, offs, srcs, mean);

    sage_linear2<<<2048, 256, 0, stream>>>(x, mean, Wl, bl, Wr, out);
}

// Round 4
// 156.846 us; speedup vs baseline: 2.0437x; 2.0437x over previous
//
#include <hip/hip_runtime.h>

#define N_NODES 50000
#define IN_DIM 64
#define OUT_DIM 128
#define N_EDGES 800000
#define NTILES ((N_NODES + 255) / 256)   // 196
#define LSTRIDE 68                        // 64 + 4 pad: bank step 4 -> <=2-way (free)

// ---------------- Phase 1: histogram of dst into offs (counts) ----------------
__global__ __launch_bounds__(256) void hist_k(const int* __restrict__ ei, int* __restrict__ offs)
{
    int e = blockIdx.x * 256 + threadIdx.x;
    if (e < N_EDGES) atomicAdd(&offs[ei[N_EDGES + e]], 1);
}

// ---------------- Phase 2a: per-tile sums ----------------
__global__ __launch_bounds__(256) void tile_sum(const int* __restrict__ offs, int* __restrict__ partials)
{
    __shared__ int ws[4];
    int t = threadIdx.x, lane = t & 63, wid = t >> 6;
    int i = blockIdx.x * 256 + t;
    int v = (i < N_NODES) ? offs[i] : 0;
#pragma unroll
    for (int d = 32; d >= 1; d >>= 1) v += __shfl_down(v, d, 64);
    if (lane == 0) ws[wid] = v;
    __syncthreads();
    if (t == 0) partials[blockIdx.x] = ws[0] + ws[1] + ws[2] + ws[3];
}

// ---------------- Phase 2b: exclusive scan of tile partials (1 wave) ----------------
__global__ __launch_bounds__(64) void scan_partials(int* __restrict__ p)
{
    int lane = threadIdx.x;
    int carry = 0;
    for (int base = 0; base < NTILES; base += 64) {
        int i = base + lane;
        int v = (i < NTILES) ? p[i] : 0;
        int incl = v;
#pragma unroll
        for (int d = 1; d < 64; d <<= 1) {
            int u = __shfl_up(incl, d, 64);
            if (lane >= d) incl += u;
        }
        if (i < NTILES) p[i] = carry + incl - v;
        carry += __shfl(incl, 63, 64);
    }
}

// ---------------- Phase 2c: per-tile exclusive rescan + add partial ----------------
__global__ __launch_bounds__(256) void scan_tile(int* __restrict__ offs, const int* __restrict__ partials)
{
    __shared__ int wsum[4];
    int t = threadIdx.x, lane = t & 63, wid = t >> 6;
    int i = blockIdx.x * 256 + t;
    int v = (i < N_NODES) ? offs[i] : 0;
    int incl = v;
#pragma unroll
    for (int d = 1; d < 64; d <<= 1) {
        int u = __shfl_up(incl, d, 64);
        if (lane >= d) incl += u;
    }
    if (lane == 63) wsum[wid] = incl;
    __syncthreads();
    int waveoff = 0;
    for (int w = 0; w < wid; ++w) waveoff += wsum[w];
    if (i < N_NODES) offs[i] = partials[blockIdx.x] + waveoff + incl - v;
}

// ---------------- Phase 3: binning (starts -> ends as side effect) ----------------
__global__ __launch_bounds__(256) void bin_k(const int* __restrict__ ei,
                                             int* __restrict__ offs, int* __restrict__ srcs)
{
    int e = blockIdx.x * 256 + threadIdx.x;
    if (e < N_EDGES) {
        int dst = ei[N_EDGES + e];
        int pos = atomicAdd(&offs[dst], 1);
        srcs[pos] = ei[e];
    }
}

// ---------------- Phase 4: gather + mean (wave per node, lane = feature) ----------------
__global__ __launch_bounds__(256) void gather_k(const float* __restrict__ x,
                                                const int* __restrict__ offs,
                                                const int* __restrict__ srcs,
                                                float* __restrict__ mean)
{
    int gw = (blockIdx.x * 256 + threadIdx.x) >> 6;
    int lane = threadIdx.x & 63;
    if (gw >= N_NODES) return;
    int n = gw;
    int end = offs[n];
    int start = n ? offs[n - 1] : 0;
    float acc = 0.f;
    int j = start;
    while (j < end) {
        int m = end - j; if (m > 64) m = 64;
        int sv = (lane < m) ? srcs[j + lane] : 0;
        int kk = 0;
        for (; kk + 4 <= m; kk += 4) {
            int s0 = __shfl(sv, kk + 0, 64);
            int s1 = __shfl(sv, kk + 1, 64);
            int s2 = __shfl(sv, kk + 2, 64);
            int s3 = __shfl(sv, kk + 3, 64);
            float a0 = x[(size_t)s0 * IN_DIM + lane];
            float a1 = x[(size_t)s1 * IN_DIM + lane];
            float a2 = x[(size_t)s2 * IN_DIM + lane];
            float a3 = x[(size_t)s3 * IN_DIM + lane];
            acc += (a0 + a1) + (a2 + a3);
        }
        for (; kk < m; ++kk) {
            int s = __shfl(sv, kk, 64);
            acc += x[(size_t)s * IN_DIM + lane];
        }
        j += m;
    }
    int deg = end - start;
    float inv = deg ? 1.0f / (float)deg : 0.0f;
    mean[(size_t)n * IN_DIM + lane] = acc * inv;
}

// ---------------- Phase 5: register-tiled linear ----------------
// Block: 64-node x 64-output tile; thread (tc=t&15, tr=t>>4) owns a 4x4 block:
// nodes n_loc = tr*4+i, outs o_loc = tc+16*j. Two phases share acc:
//   ph0: acc += x_tile . Wr_tile     ph1: acc += mean_tile . Wl_tile
// LDS stride 68 floats: read-step banks {rows: 272%32=16 -> 2-way,
// wts: 68%32=4 -> 2-way} -- both free (m136).
__global__ __launch_bounds__(256) void sage_linear3(
    const float* __restrict__ x, const float* __restrict__ mean,
    const float* __restrict__ Wl, const float* __restrict__ bl,
    const float* __restrict__ Wr, float* __restrict__ out)
{
    __shared__ float R[64 * LSTRIDE];
    __shared__ float Wt[64 * LSTRIDE];

    const int t = threadIdx.x;
    const int tc = t & 15;
    const int tr = t >> 4;
    const int tile = blockIdx.x >> 1;
    const int h = blockIdx.x & 1;       // out half: outputs h*64 .. h*64+63
    const int nbase = tile * 64;

    float acc[4][4];
#pragma unroll
    for (int i = 0; i < 4; ++i)
#pragma unroll
        for (int j = 0; j < 4; ++j) acc[i][j] = 0.f;

#pragma unroll
    for (int ph = 0; ph < 2; ++ph) {
        const float* rowsrc = ph ? mean : x;
        const float* wsrc   = ph ? Wl : Wr;
        // cooperative fill: 64x64 floats each array, float4 coalesced
#pragma unroll
        for (int it = 0; it < 4; ++it) {
            int flat = it * 1024 + t * 4;
            int nd = flat >> 6, k = flat & 63;
            int gn = nbase + nd;
            float4 rv = make_float4(0.f, 0.f, 0.f, 0.f);
            if (gn < N_NODES) rv = *(const float4*)(rowsrc + (size_t)gn * IN_DIM + k);
            *(float4*)(R + nd * LSTRIDE + k) = rv;
            float4 wv = *(const float4*)(wsrc + (size_t)(h * 64 + nd) * IN_DIM + k);
            *(float4*)(Wt + nd * LSTRIDE + k) = wv;
        }
        __syncthreads();
#pragma unroll 4
        for (int k = 0; k < 64; k += 4) {
            float4 r[4], w[4];
#pragma unroll
            for (int i = 0; i < 4; ++i) r[i] = *(const float4*)(R + (tr * 4 + i) * LSTRIDE + k);
#pragma unroll
            for (int j = 0; j < 4; ++j) w[j] = *(const float4*)(Wt + (tc + 16 * j) * LSTRIDE + k);
#pragma unroll
            for (int i = 0; i < 4; ++i)
#pragma unroll
                for (int j = 0; j < 4; ++j) {
                    acc[i][j] = fmaf(r[i].x, w[j].x, acc[i][j]);
                    acc[i][j] = fmaf(r[i].y, w[j].y, acc[i][j]);
                    acc[i][j] = fmaf(r[i].z, w[j].z, acc[i][j]);
                    acc[i][j] = fmaf(r[i].w, w[j].w, acc[i][j]);
                }
        }
        __syncthreads();
    }

    float bj[4];
#pragma unroll
    for (int j = 0; j < 4; ++j) bj[j] = bl[h * 64 + tc + 16 * j];

#pragma unroll
    for (int i = 0; i < 4; ++i) {
        int n = nbase + tr * 4 + i;
        if (n < N_NODES) {
#pragma unroll
            for (int j = 0; j < 4; ++j)
                out[(size_t)n * OUT_DIM + h * 64 + tc + 16 * j] = acc[i][j] + bj[j];
        }
    }
}

extern "C" void kernel_launch(void* const* d_in, const int* in_sizes, int n_in,
                              void* d_out, int out_size, void* d_ws, size_t ws_size,
                              hipStream_t stream) {
    const float* x  = (const float*)d_in[0];
    const int*   ei = (const int*)d_in[1];
    const float* Wl = (const float*)d_in[2];
    const float* bl = (const float*)d_in[3];
    const float* Wr = (const float*)d_in[4];
    float* out = (float*)d_out;

    int*   offs = (int*)d_ws;
    int*   srcs = offs + N_NODES;
    float* mean = (float*)(srcs + N_EDGES);
    int*   partials = (int*)(mean + (size_t)N_NODES * IN_DIM);

    hipMemsetAsync(offs, 0, (size_t)N_NODES * sizeof(int), stream);

    int eb = (N_EDGES + 255) / 256;                 // 3125
    hist_k<<<eb, 256, 0, stream>>>(ei, offs);
    tile_sum<<<NTILES, 256, 0, stream>>>(offs, partials);
    scan_partials<<<1, 64, 0, stream>>>(partials);
    scan_tile<<<NTILES, 256, 0, stream>>>(offs, partials);
    bin_k<<<eb, 256, 0, stream>>>(ei, offs, srcs);

    int gb = (N_NODES * 64 + 255) / 256;            // 12500
    gather_k<<<gb, 256, 0, stream>>>(x, offs, srcs, mean);

    int ntile = (N_NODES + 63) / 64;                // 782
    sage_linear3<<<ntile * 2, 256, 0, stream>>>(x, mean, Wl, bl, Wr, out);
}

// Round 5
// 106.039 us; speedup vs baseline: 3.0230x; 1.4791x over previous
//
#include <hip/hip_runtime.h>

#define N_NODES 50000
#define IN_DIM 64
#define OUT_DIM 128
#define N_EDGES 800000
#define LSTRIDE 68

#define NBLK 128                    // partition blocks
#define EPB (N_EDGES / NBLK)        // 6250 edges per block (exact)
#define NBUCK 196                   // ceil(50000/256) buckets of 256 dsts
#define CNT_N (NBUCK * NBLK)        // 25088
#define CNT_TILES ((CNT_N + 255) / 256)  // 98

// ---------------- A0: per-(block,bucket) histogram ----------------
__global__ __launch_bounds__(256) void bucket_count(const int* __restrict__ ei,
                                                    int* __restrict__ cnt_mat)
{
    __shared__ int h[NBUCK];
    int t = threadIdx.x, blk = blockIdx.x;
    for (int i = t; i < NBUCK; i += 256) h[i] = 0;
    __syncthreads();
    int s = blk * EPB;
    for (int i = s + t; i < s + EPB; i += 256)
        atomicAdd(&h[ei[N_EDGES + i] >> 8], 1);
    __syncthreads();
    for (int b = t; b < NBUCK; b += 256) cnt_mat[b * NBLK + blk] = h[b];
}

// ---------------- generic hierarchical exclusive scan (3 kernels) ----------------
__global__ __launch_bounds__(256) void tsum2(const int* __restrict__ in, int* __restrict__ partials, int n)
{
    __shared__ int ws[4];
    int t = threadIdx.x, lane = t & 63, wid = t >> 6;
    int i = blockIdx.x * 256 + t;
    int v = (i < n) ? in[i] : 0;
#pragma unroll
    for (int d = 32; d >= 1; d >>= 1) v += __shfl_down(v, d, 64);
    if (lane == 0) ws[wid] = v;
    __syncthreads();
    if (t == 0) partials[blockIdx.x] = ws[0] + ws[1] + ws[2] + ws[3];
}

__global__ __launch_bounds__(64) void pscan2(int* __restrict__ p, int nt)
{
    int lane = threadIdx.x;
    int carry = 0;
    for (int base = 0; base < nt; base += 64) {
        int i = base + lane;
        int v = (i < nt) ? p[i] : 0;
        int incl = v;
#pragma unroll
        for (int d = 1; d < 64; d <<= 1) {
            int u = __shfl_up(incl, d, 64);
            if (lane >= d) incl += u;
        }
        if (i < nt) p[i] = carry + incl - v;
        carry += __shfl(incl, 63, 64);
    }
}

__global__ __launch_bounds__(256) void tscan2(int* __restrict__ io, const int* __restrict__ partials, int n)
{
    __shared__ int wsum[4];
    int t = threadIdx.x, lane = t & 63, wid = t >> 6;
    int i = blockIdx.x * 256 + t;
    int v = (i < n) ? io[i] : 0;
    int incl = v;
#pragma unroll
    for (int d = 1; d < 64; d <<= 1) {
        int u = __shfl_up(incl, d, 64);
        if (lane >= d) incl += u;
    }
    if (lane == 63) wsum[wid] = incl;
    __syncthreads();
    int woff = 0;
    for (int w = 0; w < wid; ++w) woff += wsum[w];
    if (i < n) io[i] = partials[blockIdx.x] + woff + incl - v;
}

// ---------------- A1: partition edges into bucket-contiguous ebuf ----------------
__global__ __launch_bounds__(256) void bucket_place(const int* __restrict__ ei,
                                                    const int* __restrict__ cnt_scan,
                                                    uint2* __restrict__ ebuf)
{
    __shared__ int cur[NBUCK];
    int t = threadIdx.x, blk = blockIdx.x;
    for (int b = t; b < NBUCK; b += 256) cur[b] = cnt_scan[b * NBLK + blk];
    __syncthreads();
    int s = blk * EPB;
    for (int i = s + t; i < s + EPB; i += 256) {
        int src = ei[i], dst = ei[N_EDGES + i];
        int slot = atomicAdd(&cur[dst >> 8], 1);
        ebuf[slot] = make_uint2((unsigned)src, (unsigned)dst);
    }
}

// ---------------- B: final CSR within each bucket (1 block per bucket) ----------------
// Also derives offs[] ends directly: CSR base of bucket = its edge-range start.
__global__ __launch_bounds__(256) void bucket_bin(const uint2* __restrict__ ebuf,
                                                  const int* __restrict__ cnt_scan,
                                                  int* __restrict__ srcs,
                                                  int* __restrict__ offs)
{
    __shared__ int h[256];
    __shared__ int ws2[4];
    __shared__ int range_s[2];
    int t = threadIdx.x, b = blockIdx.x;
    int lane = t & 63, wid = t >> 6;
    if (t == 0) {
        range_s[0] = cnt_scan[b * NBLK];
        range_s[1] = (b < NBUCK - 1) ? cnt_scan[(b + 1) * NBLK] : N_EDGES;
    }
    h[t] = 0;
    __syncthreads();
    int bs = range_s[0], be = range_s[1];
    for (int i = bs + t; i < be; i += 256)
        atomicAdd(&h[ebuf[i].y & 255], 1);
    __syncthreads();
    int v = h[t];
    int incl = v;
#pragma unroll
    for (int d = 1; d < 64; d <<= 1) {
        int u = __shfl_up(incl, d, 64);
        if (lane >= d) incl += u;
    }
    if (lane == 63) ws2[wid] = incl;
    __syncthreads();
    int woff = 0;
    for (int w = 0; w < wid; ++w) woff += ws2[w];
    incl += woff;                    // inclusive scan over 256 dst-locals
    int ex = incl - v;
    h[t] = bs + ex;                  // per-dst cursor (safe: only self h[t] r/w)
    int node = b * 256 + t;
    if (node < N_NODES) offs[node] = bs + incl;   // end offset of node
    __syncthreads();
    for (int i = bs + t; i < be; i += 256) {
        uint2 p = ebuf[i];
        int pos = atomicAdd(&h[p.y & 255], 1);
        srcs[pos] = (int)p.x;
    }
}

// ---------------- gather + mean (wave per node, lane = feature) ----------------
__global__ __launch_bounds__(256) void gather_k(const float* __restrict__ x,
                                                const int* __restrict__ offs,
                                                const int* __restrict__ srcs,
                                                float* __restrict__ mean)
{
    int gw = (blockIdx.x * 256 + threadIdx.x) >> 6;
    int lane = threadIdx.x & 63;
    if (gw >= N_NODES) return;
    int n = gw;
    int end = offs[n];
    int start = n ? offs[n - 1] : 0;
    float acc = 0.f;
    int j = start;
    while (j < end) {
        int m = end - j; if (m > 64) m = 64;
        int sv = (lane < m) ? srcs[j + lane] : 0;
        int kk = 0;
        for (; kk + 4 <= m; kk += 4) {
            int s0 = __shfl(sv, kk + 0, 64);
            int s1 = __shfl(sv, kk + 1, 64);
            int s2 = __shfl(sv, kk + 2, 64);
            int s3 = __shfl(sv, kk + 3, 64);
            float a0 = x[(size_t)s0 * IN_DIM + lane];
            float a1 = x[(size_t)s1 * IN_DIM + lane];
            float a2 = x[(size_t)s2 * IN_DIM + lane];
            float a3 = x[(size_t)s3 * IN_DIM + lane];
            acc += (a0 + a1) + (a2 + a3);
        }
        for (; kk < m; ++kk) {
            int s = __shfl(sv, kk, 64);
            acc += x[(size_t)s * IN_DIM + lane];
        }
        j += m;
    }
    int deg = end - start;
    float inv = deg ? 1.0f / (float)deg : 0.0f;
    mean[(size_t)n * IN_DIM + lane] = acc * inv;
}

// ---------------- register-tiled linear (64-node x 64-out tile, 4x4/thread) ----------------
__global__ __launch_bounds__(256) void sage_linear3(
    const float* __restrict__ x, const float* __restrict__ mean,
    const float* __restrict__ Wl, const float* __restrict__ bl,
    const float* __restrict__ Wr, float* __restrict__ out)
{
    __shared__ float R[64 * LSTRIDE];
    __shared__ float Wt[64 * LSTRIDE];

    const int t = threadIdx.x;
    const int tc = t & 15;
    const int tr = t >> 4;
    const int tile = blockIdx.x >> 1;
    const int h = blockIdx.x & 1;
    const int nbase = tile * 64;

    float acc[4][4];
#pragma unroll
    for (int i = 0; i < 4; ++i)
#pragma unroll
        for (int j = 0; j < 4; ++j) acc[i][j] = 0.f;

#pragma unroll
    for (int ph = 0; ph < 2; ++ph) {
        const float* rowsrc = ph ? mean : x;
        const float* wsrc   = ph ? Wl : Wr;
#pragma unroll
        for (int it = 0; it < 4; ++it) {
            int flat = it * 1024 + t * 4;
            int nd = flat >> 6, k = flat & 63;
            int gn = nbase + nd;
            float4 rv = make_float4(0.f, 0.f, 0.f, 0.f);
            if (gn < N_NODES) rv = *(const float4*)(rowsrc + (size_t)gn * IN_DIM + k);
            *(float4*)(R + nd * LSTRIDE + k) = rv;
            float4 wv = *(const float4*)(wsrc + (size_t)(h * 64 + nd) * IN_DIM + k);
            *(float4*)(Wt + nd * LSTRIDE + k) = wv;
        }
        __syncthreads();
#pragma unroll 4
        for (int k = 0; k < 64; k += 4) {
            float4 r[4], w[4];
#pragma unroll
            for (int i = 0; i < 4; ++i) r[i] = *(const float4*)(R + (tr * 4 + i) * LSTRIDE + k);
#pragma unroll
            for (int j = 0; j < 4; ++j) w[j] = *(const float4*)(Wt + (tc + 16 * j) * LSTRIDE + k);
#pragma unroll
            for (int i = 0; i < 4; ++i)
#pragma unroll
                for (int j = 0; j < 4; ++j) {
                    acc[i][j] = fmaf(r[i].x, w[j].x, acc[i][j]);
                    acc[i][j] = fmaf(r[i].y, w[j].y, acc[i][j]);
                    acc[i][j] = fmaf(r[i].z, w[j].z, acc[i][j]);
                    acc[i][j] = fmaf(r[i].w, w[j].w, acc[i][j]);
                }
        }
        __syncthreads();
    }

    float bj[4];
#pragma unroll
    for (int j = 0; j < 4; ++j) bj[j] = bl[h * 64 + tc + 16 * j];

#pragma unroll
    for (int i = 0; i < 4; ++i) {
        int n = nbase + tr * 4 + i;
        if (n < N_NODES) {
#pragma unroll
            for (int j = 0; j < 4; ++j)
                out[(size_t)n * OUT_DIM + h * 64 + tc + 16 * j] = acc[i][j] + bj[j];
        }
    }
}

extern "C" void kernel_launch(void* const* d_in, const int* in_sizes, int n_in,
                              void* d_out, int out_size, void* d_ws, size_t ws_size,
                              hipStream_t stream) {
    const float* x  = (const float*)d_in[0];
    const int*   ei = (const int*)d_in[1];
    const float* Wl = (const float*)d_in[2];
    const float* bl = (const float*)d_in[3];
    const float* Wr = (const float*)d_in[4];
    float* out = (float*)d_out;

    // ws layout (16.2 MB):
    //   srcs[800000 int] | offs[50000 int] | X region (12.8 MB):
    //     X as {cnt_mat[25088] + partials[98] in first 128KB, ebuf[800000 uint2] after}
    //     X as mean[3.2M float]  -- ebuf/cnt_mat dead before gather writes mean.
    int*   srcs = (int*)d_ws;
    int*   offs = srcs + N_EDGES;
    char*  X    = (char*)(offs + N_NODES);
    int*   cnt_mat  = (int*)X;
    int*   partials = cnt_mat + CNT_N;
    uint2* ebuf     = (uint2*)(X + 131072);          // 32768 ints in, 8B aligned
    float* mean     = (float*)X;

    bucket_count<<<NBLK, 256, 0, stream>>>(ei, cnt_mat);
    tsum2<<<CNT_TILES, 256, 0, stream>>>(cnt_mat, partials, CNT_N);
    pscan2<<<1, 64, 0, stream>>>(partials, CNT_TILES);
    tscan2<<<CNT_TILES, 256, 0, stream>>>(cnt_mat, partials, CNT_N);
    bucket_place<<<NBLK, 256, 0, stream>>>(ei, cnt_mat, ebuf);
    bucket_bin<<<NBUCK, 256, 0, stream>>>(ebuf, cnt_mat, srcs, offs);

    int gb = (N_NODES * 64 + 255) / 256;            // 12500
    gather_k<<<gb, 256, 0, stream>>>(x, offs, srcs, mean);

    int ntile = (N_NODES + 63) / 64;                // 782
    sage_linear3<<<ntile * 2, 256, 0, stream>>>(x, mean, Wl, bl, Wr, out);
}